// Round 3
// baseline (236.055 us; speedup 1.0000x reference)
//
#include <hip/hip_runtime.h>
#include <hip/hip_bf16.h>

#define D_MODEL 1024
#define NH 16
#define HD 64
#define BATCH 2
#define SEQ 2048
#define M_TOTAL (BATCH*SEQ)   // 4096

typedef _Float16 f16;
typedef _Float16 half8 __attribute__((ext_vector_type(8)));
typedef _Float16 half4v __attribute__((ext_vector_type(4)));
typedef float floatx4 __attribute__((ext_vector_type(4)));

__device__ inline void gload_lds16(const void* g, void* l) {
    __builtin_amdgcn_global_load_lds(
        (const __attribute__((address_space(1))) unsigned int*)g,
        (__attribute__((address_space(3))) unsigned int*)l, 16, 0, 0);
}

// ---------------- fp32 -> fp16 cast ----------------
__global__ void cvt_f32_f16(const float* __restrict__ src, f16* __restrict__ dst, int n4) {
    int i = blockIdx.x * blockDim.x + threadIdx.x;
    if (i < n4) {
        float4 v = ((const float4*)src)[i];
        half4v o = { (f16)v.x, (f16)v.y, (f16)v.z, (f16)v.w };
        *(half4v*)(dst + (long)i * 4) = o;
    }
}

// ---------------- E = exp(mask) in f16 ----------------
__global__ void exp_cvt(const float* __restrict__ src, f16* __restrict__ dst, int n4) {
    int i = blockIdx.x * blockDim.x + threadIdx.x;
    if (i < n4) {
        float4 v = ((const float4*)src)[i];
        half4v o = { (f16)__expf(v.x), (f16)__expf(v.y), (f16)__expf(v.z), (f16)__expf(v.w) };
        *(half4v*)(dst + (long)i * 4) = o;
    }
}

// ---------------- fp32 [R][C] -> fp16 [C][R] transpose-cast ----------------
__global__ void transpose_cvt(const float* __restrict__ src, f16* __restrict__ dst, int R, int C) {
    __shared__ float tile[32][33];
    int tx = threadIdx.x;
    int ty = threadIdx.y;
    int c0 = blockIdx.x * 32;
    int r0 = blockIdx.y * 32;
    for (int yy = 0; yy < 32; yy += 8)
        tile[ty + yy][tx] = src[(long)(r0 + ty + yy) * C + c0 + tx];
    __syncthreads();
    for (int yy = 0; yy < 32; yy += 8)
        dst[(long)(c0 + ty + yy) * R + r0 + tx] = (f16)tile[tx][ty + yy];
}

// ---------------- 128xTN-tile fp16 MFMA GEMM, BK=64, XOR-swizzled LDS ----------------
// Double-buffered LDS (T3-minimal 2-phase): one barrier per K-step; next tile's
// global_load_lds issued BEFORE computing current tile so HBM/L2 latency hides
// under MFMA+ds_read. End-of-iter __syncthreads (implicit vmcnt(0) drain)
// publishes the next buffer AND proves all waves finished reading the current
// one before it is overwritten.
// A: [M][Kdim] f16; BT: [N][Kdim] f16; bias fp32 [N]
// LDS rows stride 64 f16 (unpadded, required by global_load_lds); 16B chunk at
// position p within row r holds global chunk (p ^ (r&7)) -> conflict-free b128 frag reads.
// MODE 0 (TN=128): scatter -> Qh [bh][s][d] (x0.125), Kh [bh][s][d], Vtg [bh][d][s]
// MODE 1 (TN=64):  out[m][n] = acc + bias (fp32)
template<int MODE, int TN>
__global__ __launch_bounds__(256) void gemm_mfma(
    const f16* __restrict__ A, const f16* __restrict__ BT,
    const float* __restrict__ bias,
    f16* __restrict__ Qh, f16* __restrict__ Kh, f16* __restrict__ Vtg,
    float* __restrict__ out, int Kdim)
{
    constexpr int NF = TN / 32;          // n-frags per wave
    __shared__ f16 Ah[2][128 * 64];
    __shared__ f16 Bh[2][TN * 64];
    int tid  = threadIdx.x;
    int wid  = tid >> 6;
    int lane = tid & 63;
    int quad = lane >> 4;
    int l16  = lane & 15;
    int m0 = blockIdx.y * 128;
    int n0 = blockIdx.x * TN;
    int mrow = (wid >> 1) * 64;
    int ncol = (wid & 1) * (TN / 2);
    // staging: lane -> row (lane>>3) within 8-row group, global chunk (lane&7)^(row&7)
    int grow = lane >> 3;                 // 0..7
    int gchunk = (lane & 7) ^ (grow & 7); // swizzled source chunk
    // frag-read swizzled chunk offsets (f16 units), lane-constant
    int sw0 = ((quad)     ^ (l16 & 7)) * 8;   // k-half 0
    int sw1 = ((quad + 4) ^ (l16 & 7)) * 8;   // k-half 1

    floatx4 acc[4][NF];
    #pragma unroll
    for (int mb = 0; mb < 4; mb++)
        #pragma unroll
        for (int nb = 0; nb < NF; nb++) acc[mb][nb] = (floatx4){0.f, 0.f, 0.f, 0.f};

    const f16* Abase = A + (long)m0 * Kdim;
    const f16* Bbase = BT + (long)n0 * Kdim;

    auto stage = [&](int buf, int k0) {
        #pragma unroll
        for (int j = 0; j < 4; j++) {
            int r = j * 32 + wid * 8 + grow;
            gload_lds16(Abase + (long)r * Kdim + k0 + gchunk * 8, &Ah[buf][(j * 32 + wid * 8) * 64]);
        }
        #pragma unroll
        for (int j = 0; j < TN / 32; j++) {
            int r = j * 32 + wid * 8 + grow;
            gload_lds16(Bbase + (long)r * Kdim + k0 + gchunk * 8, &Bh[buf][(j * 32 + wid * 8) * 64]);
        }
    };

    stage(0, 0);
    __syncthreads();                      // vmcnt(0) drain: buf0 ready
    int cur = 0;
    for (int k0 = 0; k0 < Kdim; k0 += 64) {
        if (k0 + 64 < Kdim) stage(cur ^ 1, k0 + 64);   // async loads fly under compute
        #pragma unroll
        for (int h = 0; h < 2; h++) {
            int sw = h ? sw1 : sw0;
            half8 af[4];
            #pragma unroll
            for (int mb = 0; mb < 4; mb++)
                af[mb] = *(const half8*)&Ah[cur][(mrow + mb * 16 + l16) * 64 + sw];
            #pragma unroll
            for (int nb = 0; nb < NF; nb++) {
                half8 bf = *(const half8*)&Bh[cur][(ncol + nb * 16 + l16) * 64 + sw];
                #pragma unroll
                for (int mb = 0; mb < 4; mb++)
                    acc[mb][nb] = __builtin_amdgcn_mfma_f32_16x16x32_f16(af[mb], bf, acc[mb][nb], 0, 0, 0);
            }
        }
        __syncthreads();                  // drains stage(cur^1); all reads of cur done
        cur ^= 1;
    }

    #pragma unroll
    for (int nb = 0; nb < NF; nb++) {
        int n = n0 + ncol + nb * 16 + l16;
        float bv = bias[n];
        int head = 0, t = 0, d = 0;
        if (MODE == 0) { head = n / 192; int rem = n % 192; t = rem / 64; d = rem % 64; }
        #pragma unroll
        for (int mb = 0; mb < 4; mb++) {
            int mbase = m0 + mrow + mb * 16 + quad * 4;
            if (MODE == 0) {
                int b = mbase >> 11;
                int s = mbase & 2047;
                long bh = b * NH + head;
                if (t == 2) {
                    half4v pack;
                    #pragma unroll
                    for (int r = 0; r < 4; r++) pack[r] = (f16)(acc[mb][nb][r] + bv);
                    *(half4v*)&Vtg[(bh * HD + d) * SEQ + s] = pack;
                } else if (t == 0) {
                    #pragma unroll
                    for (int r = 0; r < 4; r++)
                        Qh[(bh * SEQ + s + r) * HD + d] = (f16)((acc[mb][nb][r] + bv) * 0.125f);
                } else {
                    #pragma unroll
                    for (int r = 0; r < 4; r++)
                        Kh[(bh * SEQ + s + r) * HD + d] = (f16)(acc[mb][nb][r] + bv);
                }
            } else {
                #pragma unroll
                for (int r = 0; r < 4; r++)
                    out[(long)(mbase + r) * D_MODEL + n] = acc[mb][nb][r] + bv;
            }
        }
    }
}

// ---------------- flash attention v2: 8 waves x 16 q-rows, E staged via DMA ----------------
// grid (SEQ/128, B*H), 512 threads; p = E[q][key] * exp(qk/8), softmax denom deferred.
// All tiles (K, V^T, E) staged with global_load_lds + XOR chunk swizzle:
//   LDS chunk p of row r holds global chunk p ^ (r&7).
__global__ __launch_bounds__(512) void attn(
    const f16* __restrict__ Qh, const f16* __restrict__ Kh, const f16* __restrict__ Vtg,
    const f16* __restrict__ E, f16* __restrict__ valh)
{
    __shared__ f16 Kl[64 * 64];      // [key][d]
    __shared__ f16 Vt[64 * 64];      // [d][key]
    __shared__ f16 El[128 * 64];     // [q][key] tile of exp(mask)
    __shared__ f16 Pl[8][16 * 68];   // per-wave P [q][key], stride 68 (write-conflict-free)
    int tid  = threadIdx.x;
    int wid  = tid >> 6;             // 0..7
    int lane = tid & 63;
    int quad = lane >> 4;
    int l16  = lane & 15;
    int bh = blockIdx.y;
    int b  = bh >> 4;
    int h  = bh & 15;
    int qblk = blockIdx.x * 128;
    int q0 = qblk + wid * 16;

    // staging: lane -> row wid*8 + (lane>>3); LDS chunk lane&7 <- global chunk (lane&7)^(row&7)
    int wrow = wid * 8 + (lane >> 3);         // 0..63
    int kchunk = (lane & 7) ^ (wrow & 7);
    // frag-read swizzled chunk offsets (f16 units), lane-constant
    int sw0 = ((quad)     ^ (l16 & 7)) * 8;   // k-half 0
    int sw1 = ((quad + 4) ^ (l16 & 7)) * 8;   // k-half 1

    const f16* Qbase = Qh + ((long)bh * SEQ + q0) * HD;
    half8 qf[2];
    #pragma unroll
    for (int c = 0; c < 2; c++)
        qf[c] = *(const half8*)&Qbase[(long)l16 * HD + c * 32 + quad * 8];

    floatx4 Of[4];
    float sums[4];
    #pragma unroll
    for (int nb = 0; nb < 4; nb++) Of[nb] = (floatx4){0.f, 0.f, 0.f, 0.f};
    #pragma unroll
    for (int r = 0; r < 4; r++) sums[r] = 0.f;

    const f16* Kb = Kh + (long)bh * SEQ * HD;
    const f16* Vb = Vtg + (long)bh * HD * SEQ;
    const f16* Eb = E + (long)qblk * SEQ;

    for (int k0 = 0; k0 < SEQ; k0 += 64) {
        __syncthreads();
        // K: rows = keys, V: rows = d, E: rows = local q (128 rows -> two calls)
        gload_lds16(Kb + (long)(k0 + wrow) * HD + kchunk * 8, &Kl[(wid * 8) * 64]);
        gload_lds16(Vb + (long)wrow * SEQ + k0 + kchunk * 8, &Vt[(wid * 8) * 64]);
        gload_lds16(Eb + (long)wrow * SEQ + k0 + kchunk * 8, &El[(wid * 8) * 64]);
        gload_lds16(Eb + (long)(64 + wrow) * SEQ + k0 + kchunk * 8, &El[(64 + wid * 8) * 64]);
        __syncthreads();

        // QK^T: 16 q-rows x 64 keys
        floatx4 sc[4];
        #pragma unroll
        for (int kb = 0; kb < 4; kb++) {
            half8 kf0 = *(const half8*)&Kl[(kb * 16 + l16) * 64 + sw0];
            half8 kf1 = *(const half8*)&Kl[(kb * 16 + l16) * 64 + sw1];
            floatx4 s = (floatx4){0.f, 0.f, 0.f, 0.f};
            s = __builtin_amdgcn_mfma_f32_16x16x32_f16(qf[0], kf0, s, 0, 0, 0);
            s = __builtin_amdgcn_mfma_f32_16x16x32_f16(qf[1], kf1, s, 0, 0, 0);
            sc[kb] = s;
        }

        // p = E * exp(s); E read from swizzled LDS (2-way conflicts only)
        int lrow = wid * 16 + quad * 4;
        #pragma unroll
        for (int kb = 0; kb < 4; kb++) {
            int cchunk = kb * 2 + (l16 >> 3);
            #pragma unroll
            for (int r = 0; r < 4; r++) {
                int lr = lrow + r;
                f16 ev = El[lr * 64 + ((cchunk ^ (lr & 7)) * 8) + (l16 & 7)];
                float p = (float)ev * __expf(sc[kb][r]);
                sums[r] += p;
                Pl[wid][(quad * 4 + r) * 68 + kb * 16 + l16] = (f16)p;
            }
        }

        // wave-private LDS round-trip (C-layout -> A-layout); no barrier needed
        half8 pf0 = *(const half8*)&Pl[wid][l16 * 68 + quad * 8];
        half8 pf1 = *(const half8*)&Pl[wid][l16 * 68 + 32 + quad * 8];

        #pragma unroll
        for (int nb = 0; nb < 4; nb++) {
            half8 vf0 = *(const half8*)&Vt[(nb * 16 + l16) * 64 + sw0];
            half8 vf1 = *(const half8*)&Vt[(nb * 16 + l16) * 64 + sw1];
            Of[nb] = __builtin_amdgcn_mfma_f32_16x16x32_f16(pf0, vf0, Of[nb], 0, 0, 0);
            Of[nb] = __builtin_amdgcn_mfma_f32_16x16x32_f16(pf1, vf1, Of[nb], 0, 0, 0);
        }
    }

    float rinv[4];
    #pragma unroll
    for (int r = 0; r < 4; r++) {
        float s = sums[r];
        s += __shfl_xor(s, 1);
        s += __shfl_xor(s, 2);
        s += __shfl_xor(s, 4);
        s += __shfl_xor(s, 8);
        rinv[r] = 1.f / s;
    }

    #pragma unroll
    for (int nb = 0; nb < 4; nb++)
        #pragma unroll
        for (int r = 0; r < 4; r++) {
            int q = q0 + quad * 4 + r;
            int d = nb * 16 + l16;
            valh[((long)(b * SEQ + q)) * D_MODEL + h * HD + d] = (f16)(Of[nb][r] * rinv[r]);
        }
}

extern "C" void kernel_launch(void* const* d_in, const int* in_sizes, int n_in,
                              void* d_out, int out_size, void* d_ws, size_t ws_size,
                              hipStream_t stream) {
    const float* x    = (const float*)d_in[0];
    const float* mask = (const float*)d_in[1];
    const float* Wqkv = (const float*)d_in[2];
    const float* bqkv = (const float*)d_in[3];
    const float* Wout = (const float*)d_in[4];
    const float* bout = (const float*)d_in[5];
    float* out = (float*)d_out;

    char* ws = (char*)d_ws;
    f16* xh    = (f16*)(ws + 0);          // 8 MB: [4096][1024]; dead after gemm0
    f16* E     = (f16*)(ws + 0);          // 8 MB: [2048][2048] exp(mask) — overlays xh
    f16* WqkvT = (f16*)(ws + 8388608);    // 6 MB: [3072][1024]
    f16* WoutT = (f16*)(ws + 14680064);   // 2 MB: [1024][1024]
    f16* Qh    = (f16*)(ws + 16777216);   // 8 MB: [32][2048][64] (pre-scaled 1/8)
    f16* Kh    = (f16*)(ws + 25165824);   // 8 MB: [32][2048][64]
    f16* Vtg   = (f16*)(ws + 33554432);   // 8 MB: [32][64][2048] (V transposed)
    f16* valh  = (f16*)(ws + 41943040);   // 8 MB: [4096][1024]

    cvt_f32_f16<<<4096, 256, 0, stream>>>(x, xh, M_TOTAL * D_MODEL / 4);
    transpose_cvt<<<dim3(96, 32), dim3(32, 8), 0, stream>>>(Wqkv, WqkvT, 1024, 3072);
    transpose_cvt<<<dim3(32, 32), dim3(32, 8), 0, stream>>>(Wout, WoutT, 1024, 1024);
    gemm_mfma<0, 128><<<dim3(24, 32), 256, 0, stream>>>(xh, WqkvT, bqkv, Qh, Kh, Vtg, nullptr, 1024);
    exp_cvt<<<4096, 256, 0, stream>>>(mask, E, SEQ * SEQ / 4);   // xh dead now
    attn<<<dim3(16, 32), 512, 0, stream>>>(Qh, Kh, Vtg, E, valh);
    gemm_mfma<1, 64><<<dim3(16, 32), 256, 0, stream>>>(valh, WoutT, bout, nullptr, nullptr, nullptr, out, 1024);
}

// Round 4
// 219.672 us; speedup vs baseline: 1.0746x; 1.0746x over previous
//
#include <hip/hip_runtime.h>
#include <hip/hip_bf16.h>

#define D_MODEL 1024
#define NH 16
#define HD 64
#define BATCH 2
#define SEQ 2048
#define M_TOTAL (BATCH*SEQ)   // 4096

typedef _Float16 f16;
typedef _Float16 half8 __attribute__((ext_vector_type(8)));
typedef _Float16 half4v __attribute__((ext_vector_type(4)));
typedef float floatx4 __attribute__((ext_vector_type(4)));

__device__ inline void gload_lds16(const void* g, void* l) {
    __builtin_amdgcn_global_load_lds(
        (const __attribute__((address_space(1))) unsigned int*)g,
        (__attribute__((address_space(3))) unsigned int*)l, 16, 0, 0);
}

// ---------------- fp32 -> fp16 cast ----------------
__global__ void cvt_f32_f16(const float* __restrict__ src, f16* __restrict__ dst, int n4) {
    int i = blockIdx.x * blockDim.x + threadIdx.x;
    if (i < n4) {
        float4 v = ((const float4*)src)[i];
        half4v o = { (f16)v.x, (f16)v.y, (f16)v.z, (f16)v.w };
        *(half4v*)(dst + (long)i * 4) = o;
    }
}

// ---------------- E = exp(mask) in f16 ----------------
__global__ void exp_cvt(const float* __restrict__ src, f16* __restrict__ dst, int n4) {
    int i = blockIdx.x * blockDim.x + threadIdx.x;
    if (i < n4) {
        float4 v = ((const float4*)src)[i];
        half4v o = { (f16)__expf(v.x), (f16)__expf(v.y), (f16)__expf(v.z), (f16)__expf(v.w) };
        *(half4v*)(dst + (long)i * 4) = o;
    }
}

// ---------------- fp32 [R][C] -> fp16 [C][R] transpose-cast ----------------
__global__ void transpose_cvt(const float* __restrict__ src, f16* __restrict__ dst, int R, int C) {
    __shared__ float tile[32][33];
    int tx = threadIdx.x;
    int ty = threadIdx.y;
    int c0 = blockIdx.x * 32;
    int r0 = blockIdx.y * 32;
    for (int yy = 0; yy < 32; yy += 8)
        tile[ty + yy][tx] = src[(long)(r0 + ty + yy) * C + c0 + tx];
    __syncthreads();
    for (int yy = 0; yy < 32; yy += 8)
        dst[(long)(c0 + ty + yy) * R + r0 + tx] = (f16)tile[tx][ty + yy];
}

// ---------------- 128xTN-tile fp16 MFMA GEMM, BK=64, XOR-swizzled LDS ----------------
// Single-buffered (verified 50us @ 61% MfmaUtil; dbuf variant regressed via
// 64KB-LDS occupancy drop 3->2 blocks/CU).
// A: [M][Kdim] f16; BT: [N][Kdim] f16; bias fp32 [N]
// LDS rows stride 64 f16 (unpadded, required by global_load_lds); 16B chunk at
// position p within row r holds global chunk (p ^ (r&7)) -> conflict-free b128 frag reads.
// MODE 0 (TN=128): scatter -> Qh [bh][s][d] (x0.125), Kh [bh][s][d], Vtg [bh][d][s]
// MODE 1 (TN=64):  out[m][n] = acc + bias (fp32)
template<int MODE, int TN>
__global__ __launch_bounds__(256) void gemm_mfma(
    const f16* __restrict__ A, const f16* __restrict__ BT,
    const float* __restrict__ bias,
    f16* __restrict__ Qh, f16* __restrict__ Kh, f16* __restrict__ Vtg,
    float* __restrict__ out, int Kdim)
{
    constexpr int NF = TN / 32;          // n-frags per wave
    __shared__ f16 Ah[128 * 64];
    __shared__ f16 Bh[TN * 64];
    int tid  = threadIdx.x;
    int wid  = tid >> 6;
    int lane = tid & 63;
    int quad = lane >> 4;
    int l16  = lane & 15;
    int m0 = blockIdx.y * 128;
    int n0 = blockIdx.x * TN;
    int mrow = (wid >> 1) * 64;
    int ncol = (wid & 1) * (TN / 2);
    // staging: lane -> row (lane>>3) within 8-row group, global chunk (lane&7)^(row&7)
    int grow = lane >> 3;                 // 0..7
    int gchunk = (lane & 7) ^ (grow & 7); // swizzled source chunk
    // frag-read swizzled chunk offsets (f16 units), lane-constant
    int sw0 = ((quad)     ^ (l16 & 7)) * 8;   // k-half 0
    int sw1 = ((quad + 4) ^ (l16 & 7)) * 8;   // k-half 1

    floatx4 acc[4][NF];
    #pragma unroll
    for (int mb = 0; mb < 4; mb++)
        #pragma unroll
        for (int nb = 0; nb < NF; nb++) acc[mb][nb] = (floatx4){0.f, 0.f, 0.f, 0.f};

    const f16* Abase = A + (long)m0 * Kdim;
    const f16* Bbase = BT + (long)n0 * Kdim;

    for (int k0 = 0; k0 < Kdim; k0 += 64) {
        #pragma unroll
        for (int j = 0; j < 4; j++) {
            int r = j * 32 + wid * 8 + grow;
            gload_lds16(Abase + (long)r * Kdim + k0 + gchunk * 8, &Ah[(j * 32 + wid * 8) * 64]);
        }
        #pragma unroll
        for (int j = 0; j < TN / 32; j++) {
            int r = j * 32 + wid * 8 + grow;
            gload_lds16(Bbase + (long)r * Kdim + k0 + gchunk * 8, &Bh[(j * 32 + wid * 8) * 64]);
        }
        __syncthreads();
        #pragma unroll
        for (int h = 0; h < 2; h++) {
            int sw = h ? sw1 : sw0;
            half8 af[4];
            #pragma unroll
            for (int mb = 0; mb < 4; mb++)
                af[mb] = *(const half8*)&Ah[(mrow + mb * 16 + l16) * 64 + sw];
            #pragma unroll
            for (int nb = 0; nb < NF; nb++) {
                half8 bf = *(const half8*)&Bh[(ncol + nb * 16 + l16) * 64 + sw];
                #pragma unroll
                for (int mb = 0; mb < 4; mb++)
                    acc[mb][nb] = __builtin_amdgcn_mfma_f32_16x16x32_f16(af[mb], bf, acc[mb][nb], 0, 0, 0);
            }
        }
        __syncthreads();
    }

    #pragma unroll
    for (int nb = 0; nb < NF; nb++) {
        int n = n0 + ncol + nb * 16 + l16;
        float bv = bias[n];
        int head = 0, t = 0, d = 0;
        if (MODE == 0) { head = n / 192; int rem = n % 192; t = rem / 64; d = rem % 64; }
        #pragma unroll
        for (int mb = 0; mb < 4; mb++) {
            int mbase = m0 + mrow + mb * 16 + quad * 4;
            if (MODE == 0) {
                int b = mbase >> 11;
                int s = mbase & 2047;
                long bh = b * NH + head;
                if (t == 2) {
                    half4v pack;
                    #pragma unroll
                    for (int r = 0; r < 4; r++) pack[r] = (f16)(acc[mb][nb][r] + bv);
                    *(half4v*)&Vtg[(bh * HD + d) * SEQ + s] = pack;
                } else if (t == 0) {
                    #pragma unroll
                    for (int r = 0; r < 4; r++)
                        Qh[(bh * SEQ + s + r) * HD + d] = (f16)((acc[mb][nb][r] + bv) * 0.125f);
                } else {
                    #pragma unroll
                    for (int r = 0; r < 4; r++)
                        Kh[(bh * SEQ + s + r) * HD + d] = (f16)(acc[mb][nb][r] + bv);
                }
            } else {
                #pragma unroll
                for (int r = 0; r < 4; r++)
                    out[(long)(mbase + r) * D_MODEL + n] = acc[mb][nb][r] + bv;
            }
        }
    }
}

// ---------------- flash attention v3: K/V double-buffer, ONE barrier per k-tile ----------
// grid (SEQ/128, B*H), 512 threads, 8 waves x 16 q-rows.
// Iter t: stage K/V tile t+1 into buf^1 (async DMA), compute QK/softmax/PV from buf,
// prefetch E regs for t+1 mid-compute, then single __syncthreads (its vmcnt(0) drain
// publishes buf^1 AND proves all reads of buf done before t+1 overwrites it).
// E = exp(mask) read per-lane into registers (wave-private, no barrier coupling).
// LDS = 2*8K (K) + 2*8K (V) + 17K (P) = 50176 B — unchanged from v2.
__global__ __launch_bounds__(512) void attn(
    const f16* __restrict__ Qh, const f16* __restrict__ Kh, const f16* __restrict__ Vtg,
    const f16* __restrict__ E, f16* __restrict__ valh)
{
    __shared__ f16 Kl[2][64 * 64];   // [buf][key][d], swizzled chunks
    __shared__ f16 Vt[2][64 * 64];   // [buf][d][key], swizzled chunks
    __shared__ f16 Pl[8][16 * 68];   // per-wave P [q][key], stride 68 (write-conflict-free)
    int tid  = threadIdx.x;
    int wid  = tid >> 6;             // 0..7
    int lane = tid & 63;
    int quad = lane >> 4;
    int l16  = lane & 15;
    int bh = blockIdx.y;
    int b  = bh >> 4;
    int h  = bh & 15;
    int qblk = blockIdx.x * 128;
    int q0 = qblk + wid * 16;

    // staging: lane -> row wid*8 + (lane>>3); LDS chunk lane&7 <- global chunk (lane&7)^(row&7)
    int wrow = wid * 8 + (lane >> 3);         // 0..63
    int kchunk = (lane & 7) ^ (wrow & 7);
    // frag-read swizzled chunk offsets (f16 units), lane-constant
    int sw0 = ((quad)     ^ (l16 & 7)) * 8;   // k-half 0
    int sw1 = ((quad + 4) ^ (l16 & 7)) * 8;   // k-half 1

    const f16* Qbase = Qh + ((long)bh * SEQ + q0) * HD;
    half8 qf[2];
    #pragma unroll
    for (int c = 0; c < 2; c++)
        qf[c] = *(const half8*)&Qbase[(long)l16 * HD + c * 32 + quad * 8];

    floatx4 Of[4];
    float sums[4];
    #pragma unroll
    for (int nb = 0; nb < 4; nb++) Of[nb] = (floatx4){0.f, 0.f, 0.f, 0.f};
    #pragma unroll
    for (int r = 0; r < 4; r++) sums[r] = 0.f;

    const f16* Kb = Kh + (long)bh * SEQ * HD;
    const f16* Vb = Vtg + (long)bh * HD * SEQ;
    const f16* Eb = E + (long)qblk * SEQ;

    auto stage = [&](int buf, int k0) {
        gload_lds16(Kb + (long)(k0 + wrow) * HD + kchunk * 8, &Kl[buf][(wid * 8) * 64]);
        gload_lds16(Vb + (long)wrow * SEQ + k0 + kchunk * 8, &Vt[buf][(wid * 8) * 64]);
    };
    auto loadE = [&](f16 (&ef)[4][4], int k0) {
        #pragma unroll
        for (int r = 0; r < 4; r++) {
            const f16* Erow = Eb + (long)(wid * 16 + quad * 4 + r) * SEQ + k0 + l16;
            #pragma unroll
            for (int kb = 0; kb < 4; kb++) ef[r][kb] = Erow[kb * 16];
        }
    };

    f16 efA[4][4], efB[4][4];
    stage(0, 0);
    loadE(efA, 0);
    __syncthreads();                  // vmcnt(0) drain: buf0 + efA ready

    auto iter = [&](const int buf, f16 (&efC)[4][4], f16 (&efN)[4][4], int k0) {
        bool notlast = (k0 + 64 < SEQ);
        if (notlast) stage(buf ^ 1, k0 + 64);   // DMA flies under this iter's compute

        // QK^T: 16 q-rows x 64 keys
        floatx4 sc[4];
        #pragma unroll
        for (int kb = 0; kb < 4; kb++) {
            half8 kf0 = *(const half8*)&Kl[buf][(kb * 16 + l16) * 64 + sw0];
            half8 kf1 = *(const half8*)&Kl[buf][(kb * 16 + l16) * 64 + sw1];
            floatx4 s = (floatx4){0.f, 0.f, 0.f, 0.f};
            s = __builtin_amdgcn_mfma_f32_16x16x32_f16(qf[0], kf0, s, 0, 0, 0);
            s = __builtin_amdgcn_mfma_f32_16x16x32_f16(qf[1], kf1, s, 0, 0, 0);
            sc[kb] = s;
        }

        // p = E * exp(s)
        #pragma unroll
        for (int kb = 0; kb < 4; kb++)
            #pragma unroll
            for (int r = 0; r < 4; r++) {
                float p = (float)efC[r][kb] * __expf(sc[kb][r]);
                sums[r] += p;
                Pl[wid][(quad * 4 + r) * 68 + kb * 16 + l16] = (f16)p;
            }

        if (notlast) loadE(efN, k0 + 64);       // E prefetch hides under PV + next QK

        // wave-private LDS round-trip (C-layout -> A-layout); no barrier needed
        half8 pf0 = *(const half8*)&Pl[wid][l16 * 68 + quad * 8];
        half8 pf1 = *(const half8*)&Pl[wid][l16 * 68 + 32 + quad * 8];

        #pragma unroll
        for (int nb = 0; nb < 4; nb++) {
            half8 vf0 = *(const half8*)&Vt[buf][(nb * 16 + l16) * 64 + sw0];
            half8 vf1 = *(const half8*)&Vt[buf][(nb * 16 + l16) * 64 + sw1];
            Of[nb] = __builtin_amdgcn_mfma_f32_16x16x32_f16(pf0, vf0, Of[nb], 0, 0, 0);
            Of[nb] = __builtin_amdgcn_mfma_f32_16x16x32_f16(pf1, vf1, Of[nb], 0, 0, 0);
        }

        __syncthreads();  // drains stage(buf^1); proves all reads of buf done
    };

    for (int k0 = 0; k0 < SEQ; k0 += 128) {
        iter(0, efA, efB, k0);
        iter(1, efB, efA, k0 + 64);
    }

    float rinv[4];
    #pragma unroll
    for (int r = 0; r < 4; r++) {
        float s = sums[r];
        s += __shfl_xor(s, 1);
        s += __shfl_xor(s, 2);
        s += __shfl_xor(s, 4);
        s += __shfl_xor(s, 8);
        rinv[r] = 1.f / s;
    }

    #pragma unroll
    for (int nb = 0; nb < 4; nb++)
        #pragma unroll
        for (int r = 0; r < 4; r++) {
            int q = q0 + quad * 4 + r;
            int d = nb * 16 + l16;
            valh[((long)(b * SEQ + q)) * D_MODEL + h * HD + d] = (f16)(Of[nb][r] * rinv[r]);
        }
}

extern "C" void kernel_launch(void* const* d_in, const int* in_sizes, int n_in,
                              void* d_out, int out_size, void* d_ws, size_t ws_size,
                              hipStream_t stream) {
    const float* x    = (const float*)d_in[0];
    const float* mask = (const float*)d_in[1];
    const float* Wqkv = (const float*)d_in[2];
    const float* bqkv = (const float*)d_in[3];
    const float* Wout = (const float*)d_in[4];
    const float* bout = (const float*)d_in[5];
    float* out = (float*)d_out;

    char* ws = (char*)d_ws;
    f16* xh    = (f16*)(ws + 0);          // 8 MB: [4096][1024]; dead after gemm0
    f16* E     = (f16*)(ws + 0);          // 8 MB: [2048][2048] exp(mask) — overlays xh
    f16* WqkvT = (f16*)(ws + 8388608);    // 6 MB: [3072][1024]
    f16* WoutT = (f16*)(ws + 14680064);   // 2 MB: [1024][1024]
    f16* Qh    = (f16*)(ws + 16777216);   // 8 MB: [32][2048][64] (pre-scaled 1/8)
    f16* Kh    = (f16*)(ws + 25165824);   // 8 MB: [32][2048][64]
    f16* Vtg   = (f16*)(ws + 33554432);   // 8 MB: [32][64][2048] (V transposed)
    f16* valh  = (f16*)(ws + 41943040);   // 8 MB: [4096][1024]

    cvt_f32_f16<<<4096, 256, 0, stream>>>(x, xh, M_TOTAL * D_MODEL / 4);
    transpose_cvt<<<dim3(96, 32), dim3(32, 8), 0, stream>>>(Wqkv, WqkvT, 1024, 3072);
    transpose_cvt<<<dim3(32, 32), dim3(32, 8), 0, stream>>>(Wout, WoutT, 1024, 1024);
    gemm_mfma<0, 128><<<dim3(24, 32), 256, 0, stream>>>(xh, WqkvT, bqkv, Qh, Kh, Vtg, nullptr, 1024);
    exp_cvt<<<4096, 256, 0, stream>>>(mask, E, SEQ * SEQ / 4);   // xh dead now
    attn<<<dim3(16, 32), 512, 0, stream>>>(Qh, Kh, Vtg, E, valh);
    gemm_mfma<1, 64><<<dim3(16, 32), 256, 0, stream>>>(valh, WoutT, bout, nullptr, nullptr, nullptr, out, 1024);
}